// Round 6
// baseline (193.621 us; speedup 1.0000x reference)
//
#include <hip/hip_runtime.h>

typedef unsigned short u16;
typedef __attribute__((ext_vector_type(8))) short bf16x8;
typedef __attribute__((ext_vector_type(4))) float f32x4;
typedef __attribute__((ext_vector_type(16))) float f32x16;
typedef __attribute__((ext_vector_type(4))) unsigned u32x4;

#define B_ 2
#define N_ 2048
#define C_ 1024
#define H_ 16
#define D_ 64
#define M_ (B_ * N_)  // 4096

// 0.125 * log2(e): fold the 1/sqrt(D) scale and exp->exp2 conversion into Q.
#define QSCALE 0.18033688011114336f

// raw v_exp_f32 (1 instruction; |args| < ~30 here, far inside normal range)
#define EXP2R(x) __builtin_amdgcn_exp2f(x)

// round-half-up f32->bf16 (0.5 ulp, plenty under the 2% threshold)
__device__ __forceinline__ u16 f2bf(float f) {
    union { float f; unsigned u; } x; x.f = f;
    return (u16)((x.u + 0x8000u) >> 16);
}
// pack two f32 -> bf16x2 in 3 VALU ops (2 adds + v_perm); low = a, high = b
__device__ __forceinline__ unsigned pack2bf(float a, float b) {
    union { float f; unsigned u; } x, y; x.f = a; y.f = b;
    return __builtin_amdgcn_perm(y.u + 0x8000u, x.u + 0x8000u, 0x07060302);
}
// single-op pack (RTNE): low = bf16(a), high = bf16(b)  [T12 recipe: no builtin on gfx950]
__device__ __forceinline__ unsigned cvtpk2bf(float a, float b) {
    unsigned r;
    asm("v_cvt_pk_bf16_f32 %0, %1, %2" : "=v"(r) : "v"(a), "v"(b));
    return r;
}

// async global->LDS, 16B per lane. LDS dest is wave-uniform base; HW adds lane*16.
__device__ __forceinline__ void async_copy16(const void* gsrc, void* ldst) {
    __builtin_amdgcn_global_load_lds(
        (__attribute__((address_space(1))) void*)gsrc,
        (__attribute__((address_space(3))) void*)ldst,
        16, 0, 0);
}

// ---------------- fused cast fp32 -> bf16 (x, w_qkv, w_proj in one launch) ----------------
__global__ void cast3_kernel(const float* __restrict__ x, const float* __restrict__ wq,
                             const float* __restrict__ wp, u16* __restrict__ xo,
                             u16* __restrict__ wqo, u16* __restrict__ wpo) {
    int b = blockIdx.x;
    const float* s; u16* d;
    if (b < 4096)      { s = x;  d = xo;  }
    else if (b < 7168) { s = wq; d = wqo; b -= 4096; }
    else               { s = wp; d = wpo; b -= 7168; }
    int i = (b * 256 + threadIdx.x) * 4;
    const float4 v = *(const float4*)(s + i);
    uint2 o;
    o.x = pack2bf(v.x, v.y);
    o.y = pack2bf(v.z, v.w);
    *(uint2*)(d + i) = o;
}

// ---------------- GEMM C = A * B^T  (A:[M,K], Bm:[N,K], both bf16 row-major) ----------------
// EPI 0: scatter q (pre-scaled) / k into [B,H,N,D]; V written TRANSPOSED into vt [B,H,D,N].
// EPI 1: fp32 out + bias.
// Block mapping: bijective XCD swizzle (grid % 8 == 0 for both launches).
template <int EPI>
__global__ __launch_bounds__(256, 3) void gemm_bt(
    const u16* __restrict__ A, const u16* __restrict__ Bm,
    int M, int Ncols, int K, int ntiles_n,
    u16* __restrict__ qo, u16* __restrict__ ko, u16* __restrict__ vt,
    const float* __restrict__ bias, float* __restrict__ out) {
    __shared__ u16 As[128 * 64];
    __shared__ u16 Bs[128 * 64];
    const int tid = threadIdx.x, lane = tid & 63, w = tid >> 6;
    const int cpx = gridDim.x >> 3;
    const int sbid = (blockIdx.x & 7) * cpx + (blockIdx.x >> 3);
    const int bx = sbid % ntiles_n, by = sbid / ntiles_n;
    const int m0 = by * 128, n0 = bx * 128;
    const int wm = w >> 1, wn = w & 1;
    const int q16 = lane >> 4, l15 = lane & 15;
    const int r0 = lane >> 3, c0 = (lane & 7) * 8;
    f32x4 acc[4][4] = {};

    for (int k0 = 0; k0 < K; k0 += 64) {
#pragma unroll
        for (int i = 0; i < 4; ++i) {
            int blk = w * 4 + i;
            int r = blk * 8 + r0;
            async_copy16(A + (size_t)(m0 + r) * K + k0 + c0, (char*)As + blk * 1024);
            async_copy16(Bm + (size_t)(n0 + r) * K + k0 + c0, (char*)Bs + blk * 1024);
        }
        __builtin_amdgcn_s_waitcnt(0);
        __syncthreads();
#pragma unroll
        for (int ks = 0; ks < 2; ++ks) {
            bf16x8 af[4], bf[4];
#pragma unroll
            for (int i = 0; i < 4; ++i) {
                af[i] = *(const bf16x8*)&As[(wm * 64 + i * 16 + l15) * 64 + ks * 32 + q16 * 8];
                bf[i] = *(const bf16x8*)&Bs[(wn * 64 + i * 16 + l15) * 64 + ks * 32 + q16 * 8];
            }
#pragma unroll
            for (int mi = 0; mi < 4; ++mi)
#pragma unroll
                for (int ni = 0; ni < 4; ++ni)
                    acc[mi][ni] = __builtin_amdgcn_mfma_f32_16x16x32_bf16(af[mi], bf[ni], acc[mi][ni], 0, 0, 0);
        }
        __syncthreads();
    }

#pragma unroll
    for (int mi = 0; mi < 4; ++mi) {
#pragma unroll
        for (int ni = 0; ni < 4; ++ni) {
            int n_g = n0 + wn * 64 + ni * 16 + l15;
            if (EPI == 0) {
                int which = n_g >> 10;           // block-uniform: 0=q 1=k 2=v
                int h = (n_g >> 6) & 15;
                int d = n_g & 63;
                int m_base = m0 + wm * 64 + mi * 16 + q16 * 4;
                int b = m_base >> 11;
                int nn0 = m_base & 2047;
                if (which == 2) {
                    uint2 pk;
                    pk.x = pack2bf(acc[mi][ni][0], acc[mi][ni][1]);
                    pk.y = pack2bf(acc[mi][ni][2], acc[mi][ni][3]);
                    *(uint2*)(vt + ((size_t)((b * H_ + h) * D_ + d) << 11) + nn0) = pk;
                } else {
                    size_t base = ((size_t)((b * H_ + h) * N_ + nn0) << 6) + d;
#pragma unroll
                    for (int r = 0; r < 4; ++r) {
                        float v = acc[mi][ni][r];
                        if (which == 0) qo[base + (size_t)r * D_] = f2bf(v * QSCALE);
                        else            ko[base + (size_t)r * D_] = f2bf(v);
                    }
                }
            } else {
#pragma unroll
                for (int r = 0; r < 4; ++r) {
                    int m_g = m0 + wm * 64 + mi * 16 + q16 * 4 + r;
                    out[(size_t)m_g * Ncols + n_g] = acc[mi][ni][r] + bias[n_g];
                }
            }
        }
    }
}

// ---------------- attention: 32x32 MFMA, 64 q/wave, in-register P, XCD-swizzled ---------
// grid: 32 bh * 8 q-blocks of 256 -> 256 blocks = 1 block/CU; 4 waves x 64 q; LDS 64 KB.
// r5 accounting: LDS array was top consumer (4096 b128 reads/CU x ~16cyc = 57%), MFMA 29%,
// VALU 44%. Fix: each wave owns TWO 32-q groups -> every kf/vf LDS read feeds 2 MFMAs
// (read:MFMA cycle ratio 12:16 instead of 12:8). LDS reads/CU halve; MFMA becomes the
// larger pipe. VALU trimmed via 1-op v_cvt_pk_bf16_f32 (was 3-op pack2bf).
// QK C-layout (m74/m101): col=lane&31=q, row=key=(reg&3)+8*(reg>>2)+4*hi.
__global__ __launch_bounds__(256, 1) void attn_kernel(
    const u16* __restrict__ Q, const u16* __restrict__ K,
    const u16* __restrict__ VT, u16* __restrict__ O) {
    __shared__ u16 Ks[2][2][64 * 64];  // [buf][sub][key][d], 16B-block swizzle (mask 7)
    __shared__ u16 Vs[2][2][64 * 64];  // [buf][sub][d][key], 16B-block swizzle (mask 7)
    const int tid = threadIdx.x, lane = tid & 63, w = tid >> 6;  // w = 0..3
    const int l31 = lane & 31, hi = lane >> 5, l7 = l31 & 7;
    const int bid = blockIdx.x;
    // bijective XCD swizzle over 256 blocks: xcd=bid&7, qb=(bid>>3)&7, hi4=bid>>6
    const int bh = (bid & 7) * 4 + (bid >> 6);
    const int q0 = ((bid >> 3) & 7) * 256;
    const size_t head = (size_t)bh * N_ * D_;
    const int lr3 = lane >> 3, lc7 = lane & 7;

    auto stage = [&](int kt, int buf) {
        int key0 = kt * 128;
#pragma unroll
        for (int s = 0; s < 2; ++s)
#pragma unroll
            for (int i = 0; i < 2; ++i) {
                int c = w * 2 + i;  // 1KB chunk 0..7 of each 8KB sub-tile
                int row = c * 8 + lr3;
                async_copy16(K + head + (size_t)(key0 + s * 64 + row) * D_ + (lc7 ^ lr3) * 8,
                             (char*)Ks[buf][s] + c * 1024);
                async_copy16(VT + head + (size_t)row * N_ + key0 + s * 64 + (lc7 ^ lr3) * 8,
                             (char*)Vs[buf][s] + c * 1024);
            }
    };

    // prologue: Q B-fragments for both q-groups (q = q0 + w*64 + qg*32 + l31).
    bf16x8 qf[2][4];
#pragma unroll
    for (int qg = 0; qg < 2; ++qg)
#pragma unroll
        for (int ds = 0; ds < 4; ++ds)
            qf[qg][ds] = *(const bf16x8*)(Q + head +
                (size_t)(q0 + w * 64 + qg * 32 + l31) * D_ + ds * 16 + hi * 8);
    stage(0, 0);
    __builtin_amdgcn_s_waitcnt(0);
    __syncthreads();

    f32x16 o_acc[2][2] = {};  // [qg][db]
    float rs[2] = {0.f, 0.f};

    for (int kt = 0; kt < 16; ++kt) {
        int buf = kt & 1;
        stage((kt + 1) & 15, buf ^ 1);  // prefetch next 128-key tile (kt=15 wraps, harmless)

#pragma unroll
        for (int s = 0; s < 2; ++s) {
#pragma unroll
            for (int kb2 = 0; kb2 < 2; ++kb2) {
                // QK: S^T = K·Q^T over d=64; kf read ONCE, feeds both q-groups
                bf16x8 kf[4];
#pragma unroll
                for (int ds = 0; ds < 4; ++ds)
                    kf[ds] = *(const bf16x8*)&Ks[buf][s][(kb2 * 32 + l31) * 64 + ((ds * 2 + hi) ^ l7) * 8];
                f32x16 st0 = {}, st1 = {};
                __builtin_amdgcn_s_setprio(1);
#pragma unroll
                for (int ds = 0; ds < 4; ++ds) {
                    st0 = __builtin_amdgcn_mfma_f32_32x32x16_bf16(kf[ds], qf[0][ds], st0, 0, 0, 0);
                    st1 = __builtin_amdgcn_mfma_f32_32x32x16_bf16(kf[ds], qf[1][ds], st1, 0, 0, 0);
                }
                __builtin_amdgcn_s_setprio(0);

                // softmax numerator + rowsum + in-register A-fragment build, per q-group
                union { u32x4 u; bf16x8 v; } af0[2], af1[2];
#pragma unroll
                for (int qg = 0; qg < 2; ++qg) {
                    const f32x16& st = qg ? st1 : st0;
                    float p[16];
#pragma unroll
                    for (int i = 0; i < 16; ++i) p[i] = EXP2R(st[i]);
#pragma unroll
                    for (int i = 0; i < 16; ++i) rs[qg] += p[i];
                    // pack pairs (1 op each), then swap upper(a) <-> lower(b) across lane+-32
                    unsigned a0 = cvtpk2bf(p[0], p[1]),   b0 = cvtpk2bf(p[4], p[5]);
                    unsigned a1 = cvtpk2bf(p[2], p[3]),   b1 = cvtpk2bf(p[6], p[7]);
                    unsigned a2 = cvtpk2bf(p[8], p[9]),   b2 = cvtpk2bf(p[12], p[13]);
                    unsigned a3 = cvtpk2bf(p[10], p[11]), b3 = cvtpk2bf(p[14], p[15]);
                    asm("v_permlane32_swap_b32 %0, %1" : "+v"(a0), "+v"(b0));
                    asm("v_permlane32_swap_b32 %0, %1" : "+v"(a1), "+v"(b1));
                    asm("v_permlane32_swap_b32 %0, %1" : "+v"(a2), "+v"(b2));
                    asm("v_permlane32_swap_b32 %0, %1" : "+v"(a3), "+v"(b3));
                    af0[qg].u = (u32x4){a0, a1, b0, b1};  // keys kb2*32 + 0..15
                    af1[qg].u = (u32x4){a2, a3, b2, b3};  // keys kb2*32 + 16..31
                }

                // PV: O += P·V; vf read ONCE, feeds both q-groups
                __builtin_amdgcn_s_setprio(1);
#pragma unroll
                for (int db = 0; db < 2; ++db) {
                    bf16x8 vf0 = *(const bf16x8*)&Vs[buf][s][(db * 32 + l31) * 64 + ((kb2 * 4 + hi) ^ l7) * 8];
                    o_acc[0][db] = __builtin_amdgcn_mfma_f32_32x32x16_bf16(af0[0].v, vf0, o_acc[0][db], 0, 0, 0);
                    o_acc[1][db] = __builtin_amdgcn_mfma_f32_32x32x16_bf16(af0[1].v, vf0, o_acc[1][db], 0, 0, 0);
                    bf16x8 vf1 = *(const bf16x8*)&Vs[buf][s][(db * 32 + l31) * 64 + ((kb2 * 4 + 2 + hi) ^ l7) * 8];
                    o_acc[0][db] = __builtin_amdgcn_mfma_f32_32x32x16_bf16(af1[0].v, vf1, o_acc[0][db], 0, 0, 0);
                    o_acc[1][db] = __builtin_amdgcn_mfma_f32_32x32x16_bf16(af1[1].v, vf1, o_acc[1][db], 0, 0, 0);
                }
                __builtin_amdgcn_s_setprio(0);
            }
        }

        // single full drain + barrier per 128 keys (4-wave barrier)
        __builtin_amdgcn_s_waitcnt(0);
        __syncthreads();
    }

    // rowsum fold + normalize + store, per q-group
    const int b = bh >> 4, h = bh & 15;
#pragma unroll
    for (int qg = 0; qg < 2; ++qg) {
        rs[qg] += __shfl_xor(rs[qg], 32);
        float rsi = 1.0f / rs[qg];  // valid for q = l31 on every lane
#pragma unroll
        for (int reg = 0; reg < 16; ++reg) {
            int qrow = (reg & 3) + 8 * (reg >> 2) + 4 * hi;  // O row for this acc reg
            float inv = __shfl(rsi, qrow);                    // lane qrow holds 1/rs for q=qrow
            int qg_g = q0 + w * 64 + qg * 32 + qrow;
#pragma unroll
            for (int db = 0; db < 2; ++db) {
                int d = db * 32 + l31;
                O[((size_t)(b * N_ + qg_g) << 10) + h * 64 + d] = f2bf(o_acc[qg][db][reg] * inv);
            }
        }
    }
}

extern "C" void kernel_launch(void* const* d_in, const int* in_sizes, int n_in,
                              void* d_out, int out_size, void* d_ws, size_t ws_size,
                              hipStream_t stream) {
    const float* x      = (const float*)d_in[0];
    const float* w_qkv  = (const float*)d_in[1];
    const float* w_proj = (const float*)d_in[2];
    const float* b_proj = (const float*)d_in[3];
    float* out = (float*)d_out;

    char* ws = (char*)d_ws;
    const size_t MB = 1024 * 1024;
    u16* x_bf     = (u16*)(ws + 0 * MB);   // 8 MB
    u16* wqkv_bf  = (u16*)(ws + 8 * MB);   // 6 MB
    u16* wproj_bf = (u16*)(ws + 14 * MB);  // 2 MB
    u16* q_bf     = (u16*)(ws + 16 * MB);  // 8 MB [B,H,N,D]
    u16* k_bf     = (u16*)(ws + 24 * MB);  // 8 MB [B,H,N,D]
    u16* vt_bf    = (u16*)(ws + 32 * MB);  // 8 MB [B,H,D,N]
    u16* ao_bf    = (u16*)(ws + 40 * MB);  // 8 MB [B,N,C]

    cast3_kernel<<<8192, 256, 0, stream>>>(x, w_qkv, w_proj, x_bf, wqkv_bf, wproj_bf);

    gemm_bt<0><<<32 * 24, 256, 0, stream>>>(x_bf, wqkv_bf, M_, 3 * C_, C_, 24,
                                            q_bf, k_bf, vt_bf, nullptr, nullptr);

    attn_kernel<<<256, 256, 0, stream>>>(q_bf, k_bf, vt_bf, ao_bf);

    gemm_bt<1><<<32 * 8, 256, 0, stream>>>(ao_bf, wproj_bf, M_, C_, C_, 8,
                                           nullptr, nullptr, nullptr, b_proj, out);
}

// Round 8
// 184.780 us; speedup vs baseline: 1.0478x; 1.0478x over previous
//
#include <hip/hip_runtime.h>

typedef unsigned short u16;
typedef __attribute__((ext_vector_type(8))) short bf16x8;
typedef __attribute__((ext_vector_type(4))) float f32x4;
typedef __attribute__((ext_vector_type(16))) float f32x16;
typedef __attribute__((ext_vector_type(4))) unsigned u32x4;

#define B_ 2
#define N_ 2048
#define C_ 1024
#define H_ 16
#define D_ 64
#define M_ (B_ * N_)  // 4096

// 0.125 * log2(e): fold the 1/sqrt(D) scale and exp->exp2 conversion into Q.
#define QSCALE 0.18033688011114336f

#define EXP2R(x) __builtin_amdgcn_exp2f(x)

__device__ __forceinline__ u16 f2bf(float f) {
    union { float f; unsigned u; } x; x.f = f;
    return (u16)((x.u + 0x8000u) >> 16);
}
__device__ __forceinline__ unsigned pack2bf(float a, float b) {
    union { float f; unsigned u; } x, y; x.f = a; y.f = b;
    return __builtin_amdgcn_perm(y.u + 0x8000u, x.u + 0x8000u, 0x07060302);
}
// single-op pack (RTNE), verified correct in r6
__device__ __forceinline__ unsigned cvtpk2bf(float a, float b) {
    unsigned r;
    asm("v_cvt_pk_bf16_f32 %0, %1, %2" : "=v"(r) : "v"(a), "v"(b));
    return r;
}

__device__ __forceinline__ void async_copy16(const void* gsrc, void* ldst) {
    __builtin_amdgcn_global_load_lds(
        (__attribute__((address_space(1))) void*)gsrc,
        (__attribute__((address_space(3))) void*)ldst,
        16, 0, 0);
}

// ---------------- fused cast fp32 -> bf16 (x, w_qkv, w_proj in one launch) ----------------
__global__ void cast3_kernel(const float* __restrict__ x, const float* __restrict__ wq,
                             const float* __restrict__ wp, u16* __restrict__ xo,
                             u16* __restrict__ wqo, u16* __restrict__ wpo) {
    int b = blockIdx.x;
    const float* s; u16* d;
    if (b < 4096)      { s = x;  d = xo;  }
    else if (b < 7168) { s = wq; d = wqo; b -= 4096; }
    else               { s = wp; d = wpo; b -= 7168; }
    int i = (b * 256 + threadIdx.x) * 4;
    const float4 v = *(const float4*)(s + i);
    uint2 o;
    o.x = pack2bf(v.x, v.y);
    o.y = pack2bf(v.z, v.w);
    *(uint2*)(d + i) = o;
}

// ---------------- GEMM C = A * B^T  (A:[M,K], Bm:[N,K], both bf16 row-major) ----------------
// EPI 0: scatter q (pre-scaled) / k into [B,H,N,D]; V written TRANSPOSED into vt [B,H,D,N].
// EPI 1: fp32 out + bias.
// Block mapping: bijective XCD swizzle (grid % 8 == 0 for both launches).
template <int EPI>
__global__ __launch_bounds__(256, 3) void gemm_bt(
    const u16* __restrict__ A, const u16* __restrict__ Bm,
    int M, int Ncols, int K, int ntiles_n,
    u16* __restrict__ qo, u16* __restrict__ ko, u16* __restrict__ vt,
    const float* __restrict__ bias, float* __restrict__ out) {
    __shared__ u16 As[128 * 64];
    __shared__ u16 Bs[128 * 64];
    const int tid = threadIdx.x, lane = tid & 63, w = tid >> 6;
    const int cpx = gridDim.x >> 3;
    const int sbid = (blockIdx.x & 7) * cpx + (blockIdx.x >> 3);
    const int bx = sbid % ntiles_n, by = sbid / ntiles_n;
    const int m0 = by * 128, n0 = bx * 128;
    const int wm = w >> 1, wn = w & 1;
    const int q16 = lane >> 4, l15 = lane & 15;
    const int r0 = lane >> 3, c0 = (lane & 7) * 8;
    f32x4 acc[4][4] = {};

    for (int k0 = 0; k0 < K; k0 += 64) {
#pragma unroll
        for (int i = 0; i < 4; ++i) {
            int blk = w * 4 + i;
            int r = blk * 8 + r0;
            async_copy16(A + (size_t)(m0 + r) * K + k0 + c0, (char*)As + blk * 1024);
            async_copy16(Bm + (size_t)(n0 + r) * K + k0 + c0, (char*)Bs + blk * 1024);
        }
        __builtin_amdgcn_s_waitcnt(0);
        __syncthreads();
#pragma unroll
        for (int ks = 0; ks < 2; ++ks) {
            bf16x8 af[4], bf[4];
#pragma unroll
            for (int i = 0; i < 4; ++i) {
                af[i] = *(const bf16x8*)&As[(wm * 64 + i * 16 + l15) * 64 + ks * 32 + q16 * 8];
                bf[i] = *(const bf16x8*)&Bs[(wn * 64 + i * 16 + l15) * 64 + ks * 32 + q16 * 8];
            }
#pragma unroll
            for (int mi = 0; mi < 4; ++mi)
#pragma unroll
                for (int ni = 0; ni < 4; ++ni)
                    acc[mi][ni] = __builtin_amdgcn_mfma_f32_16x16x32_bf16(af[mi], bf[ni], acc[mi][ni], 0, 0, 0);
        }
        __syncthreads();
    }

#pragma unroll
    for (int mi = 0; mi < 4; ++mi) {
#pragma unroll
        for (int ni = 0; ni < 4; ++ni) {
            int n_g = n0 + wn * 64 + ni * 16 + l15;
            if (EPI == 0) {
                int which = n_g >> 10;           // block-uniform: 0=q 1=k 2=v
                int h = (n_g >> 6) & 15;
                int d = n_g & 63;
                int m_base = m0 + wm * 64 + mi * 16 + q16 * 4;
                int b = m_base >> 11;
                int nn0 = m_base & 2047;
                if (which == 2) {
                    uint2 pk;
                    pk.x = pack2bf(acc[mi][ni][0], acc[mi][ni][1]);
                    pk.y = pack2bf(acc[mi][ni][2], acc[mi][ni][3]);
                    *(uint2*)(vt + ((size_t)((b * H_ + h) * D_ + d) << 11) + nn0) = pk;
                } else {
                    size_t base = ((size_t)((b * H_ + h) * N_ + nn0) << 6) + d;
#pragma unroll
                    for (int r = 0; r < 4; ++r) {
                        float v = acc[mi][ni][r];
                        if (which == 0) qo[base + (size_t)r * D_] = f2bf(v * QSCALE);
                        else            ko[base + (size_t)r * D_] = f2bf(v);
                    }
                }
            } else {
#pragma unroll
                for (int r = 0; r < 4; ++r) {
                    int m_g = m0 + wm * 64 + mi * 16 + q16 * 4 + r;
                    out[(size_t)m_g * Ncols + n_g] = acc[mi][ni][r] + bias[n_g];
                }
            }
        }
    }
}

// ---------------- attention: 4-wave blocks of 128 q, 2 blocks/CU, batched LDS reads ------
// grid: 32 bh * 16 q-blocks -> 512 blocks, 256 thr, LDS 32 KB -> 2 blocks/CU (8 waves/CU,
// 2/SIMD, but the two blocks' barriers are INDEPENDENT: one block computes while the other
// drains -- the r5 monolithic 8-wave block stalled the whole CU at each barrier).
// Per 64-key tile: batch-issue all 16 ds_read_b128 (kf both kb2 + vf all parts), then two
// independent QK MFMA chains, softmax both, two independent PV chains. Same math/addresses
// as r5 (verified); 32x32 MFMA, in-register P via cvt_pk + permlane32_swap.
// QK C-layout (m74/m101): col=lane&31=q, row=key=(reg&3)+8*(reg>>2)+4*hi.
__global__ __launch_bounds__(256, 2) void attn_kernel(
    const u16* __restrict__ Q, const u16* __restrict__ K,
    const u16* __restrict__ VT, u16* __restrict__ O) {
    __shared__ u16 Ks[2][64 * 64];  // [buf][key][d], 16B-block swizzle (mask 7)
    __shared__ u16 Vs[2][64 * 64];  // [buf][d][key], 16B-block swizzle (mask 7)
    const int tid = threadIdx.x, lane = tid & 63, w = tid >> 6;  // w = 0..3
    const int l31 = lane & 31, hi = lane >> 5, l7 = l31 & 7;
    const int bid = blockIdx.x;
    // bijective XCD swizzle over 512 blocks: xcd=bid&7, qb=(bid>>3)&15, hb=bid>>7
    const int bh = (bid & 7) * 4 + (bid >> 7);   // 4 consecutive heads per XCD (L2-resident)
    const int q0 = ((bid >> 3) & 15) * 128;
    const size_t head = (size_t)bh * N_ * D_;
    const int lr3 = lane >> 3, lc7 = lane & 7;

    auto stage = [&](int kt, int buf) {
        int key0 = kt * 64;
#pragma unroll
        for (int i = 0; i < 2; ++i) {
            int c = w * 2 + i;  // 1KB chunk 0..7 of each 8KB tile
            int row = c * 8 + lr3;
            async_copy16(K + head + (size_t)(key0 + row) * D_ + (lc7 ^ lr3) * 8,
                         (char*)Ks[buf] + c * 1024);
            async_copy16(VT + head + (size_t)row * N_ + key0 + (lc7 ^ lr3) * 8,
                         (char*)Vs[buf] + c * 1024);
        }
    };

    // prologue: Q B-fragments (q = q0 + w*32 + l31) + K/V(0) stage; full drain once.
    bf16x8 qf[4];
#pragma unroll
    for (int ds = 0; ds < 4; ++ds)
        qf[ds] = *(const bf16x8*)(Q + head + (size_t)(q0 + w * 32 + l31) * D_ + ds * 16 + hi * 8);
    stage(0, 0);
    __builtin_amdgcn_s_waitcnt(0);
    __syncthreads();

    f32x16 o_acc[2] = {};  // [db], constant-indexed only
    float rs = 0.f;

    for (int kt = 0; kt < 32; ++kt) {
        int buf = kt & 1;
        stage((kt + 1) & 31, buf ^ 1);  // prefetch next 64-key tile (kt=31 wraps, harmless)

        // ---- batch-issue all LDS reads for this tile (16 x ds_read_b128) ----
        bf16x8 kf[2][4];    // [kb2][ds] -- constant indices after unroll
        bf16x8 vlo[2][2];   // [kb2][db] k-slice (kb2*4+hi)
        bf16x8 vhi[2][2];   // [kb2][db] k-slice (kb2*4+2+hi)
#pragma unroll
        for (int kb2 = 0; kb2 < 2; ++kb2) {
#pragma unroll
            for (int ds = 0; ds < 4; ++ds)
                kf[kb2][ds] = *(const bf16x8*)&Ks[buf][(kb2 * 32 + l31) * 64 + ((ds * 2 + hi) ^ l7) * 8];
#pragma unroll
            for (int db = 0; db < 2; ++db) {
                vlo[kb2][db] = *(const bf16x8*)&Vs[buf][(db * 32 + l31) * 64 + ((kb2 * 4 + hi) ^ l7) * 8];
                vhi[kb2][db] = *(const bf16x8*)&Vs[buf][(db * 32 + l31) * 64 + ((kb2 * 4 + 2 + hi) ^ l7) * 8];
            }
        }

        // ---- QK: two independent MFMA chains (kb2 = 0,1) ----
        f32x16 st0 = {}, st1 = {};
        __builtin_amdgcn_s_setprio(1);
#pragma unroll
        for (int ds = 0; ds < 4; ++ds) {
            st0 = __builtin_amdgcn_mfma_f32_32x32x16_bf16(kf[0][ds], qf[ds], st0, 0, 0, 0);
            st1 = __builtin_amdgcn_mfma_f32_32x32x16_bf16(kf[1][ds], qf[ds], st1, 0, 0, 0);
        }
        __builtin_amdgcn_s_setprio(0);

        // ---- softmax numerators + in-register A-fragment build, both kb2 ----
        union { u32x4 u; bf16x8 v; } af0[2], af1[2];
#pragma unroll
        for (int kb2 = 0; kb2 < 2; ++kb2) {
            float p[16];
            if (kb2 == 0) {
#pragma unroll
                for (int i = 0; i < 16; ++i) p[i] = EXP2R(st0[i]);
            } else {
#pragma unroll
                for (int i = 0; i < 16; ++i) p[i] = EXP2R(st1[i]);
            }
#pragma unroll
            for (int i = 0; i < 16; ++i) rs += p[i];
            unsigned a0 = cvtpk2bf(p[0], p[1]),   b0 = cvtpk2bf(p[4], p[5]);
            unsigned a1 = cvtpk2bf(p[2], p[3]),   b1 = cvtpk2bf(p[6], p[7]);
            unsigned a2 = cvtpk2bf(p[8], p[9]),   b2 = cvtpk2bf(p[12], p[13]);
            unsigned a3 = cvtpk2bf(p[10], p[11]), b3 = cvtpk2bf(p[14], p[15]);
            asm("v_permlane32_swap_b32 %0, %1" : "+v"(a0), "+v"(b0));
            asm("v_permlane32_swap_b32 %0, %1" : "+v"(a1), "+v"(b1));
            asm("v_permlane32_swap_b32 %0, %1" : "+v"(a2), "+v"(b2));
            asm("v_permlane32_swap_b32 %0, %1" : "+v"(a3), "+v"(b3));
            af0[kb2].u = (u32x4){a0, a1, b0, b1};  // keys kb2*32 + 0..15
            af1[kb2].u = (u32x4){a2, a3, b2, b3};  // keys kb2*32 + 16..31
        }

        // ---- PV: two independent accumulator chains (db = 0,1) ----
        __builtin_amdgcn_s_setprio(1);
#pragma unroll
        for (int kb2 = 0; kb2 < 2; ++kb2) {
            o_acc[0] = __builtin_amdgcn_mfma_f32_32x32x16_bf16(af0[kb2].v, vlo[kb2][0], o_acc[0], 0, 0, 0);
            o_acc[1] = __builtin_amdgcn_mfma_f32_32x32x16_bf16(af0[kb2].v, vlo[kb2][1], o_acc[1], 0, 0, 0);
            o_acc[0] = __builtin_amdgcn_mfma_f32_32x32x16_bf16(af1[kb2].v, vhi[kb2][0], o_acc[0], 0, 0, 0);
            o_acc[1] = __builtin_amdgcn_mfma_f32_32x32x16_bf16(af1[kb2].v, vhi[kb2][1], o_acc[1], 0, 0, 0);
        }
        __builtin_amdgcn_s_setprio(0);

        // drain + barrier; prefetch had the whole phase to land
        __builtin_amdgcn_s_waitcnt(0);
        __syncthreads();
    }

    // rowsum fold + normalize + store
    rs += __shfl_xor(rs, 32);
    float rsi = 1.0f / rs;  // valid for q = l31 on every lane
    const int b = bh >> 4, h = bh & 15;
#pragma unroll
    for (int reg = 0; reg < 16; ++reg) {
        int qrow = (reg & 3) + 8 * (reg >> 2) + 4 * hi;  // O row for this acc reg
        float inv = __shfl(rsi, qrow);                    // lane qrow holds 1/rs for q=qrow
        int qg = q0 + w * 32 + qrow;
#pragma unroll
        for (int db = 0; db < 2; ++db) {
            int d = db * 32 + l31;
            O[((size_t)(b * N_ + qg) << 10) + h * 64 + d] = f2bf(o_acc[db][reg] * inv);
        }
    }
}

extern "C" void kernel_launch(void* const* d_in, const int* in_sizes, int n_in,
                              void* d_out, int out_size, void* d_ws, size_t ws_size,
                              hipStream_t stream) {
    const float* x      = (const float*)d_in[0];
    const float* w_qkv  = (const float*)d_in[1];
    const float* w_proj = (const float*)d_in[2];
    const float* b_proj = (const float*)d_in[3];
    float* out = (float*)d_out;

    char* ws = (char*)d_ws;
    const size_t MB = 1024 * 1024;
    u16* x_bf     = (u16*)(ws + 0 * MB);   // 8 MB
    u16* wqkv_bf  = (u16*)(ws + 8 * MB);   // 6 MB
    u16* wproj_bf = (u16*)(ws + 14 * MB);  // 2 MB
    u16* q_bf     = (u16*)(ws + 16 * MB);  // 8 MB [B,H,N,D]
    u16* k_bf     = (u16*)(ws + 24 * MB);  // 8 MB [B,H,N,D]
    u16* vt_bf    = (u16*)(ws + 32 * MB);  // 8 MB [B,H,D,N]
    u16* ao_bf    = (u16*)(ws + 40 * MB);  // 8 MB [B,N,C]

    cast3_kernel<<<8192, 256, 0, stream>>>(x, w_qkv, w_proj, x_bf, wqkv_bf, wproj_bf);

    gemm_bt<0><<<32 * 24, 256, 0, stream>>>(x_bf, wqkv_bf, M_, 3 * C_, C_, 24,
                                            q_bf, k_bf, vt_bf, nullptr, nullptr);

    attn_kernel<<<512, 256, 0, stream>>>(q_bf, k_bf, vt_bf, ao_bf);

    gemm_bt<1><<<32 * 8, 256, 0, stream>>>(ao_bf, wproj_bf, M_, C_, C_, 8,
                                           nullptr, nullptr, nullptr, b_proj, out);
}

// Round 9
// 178.807 us; speedup vs baseline: 1.0828x; 1.0334x over previous
//
#include <hip/hip_runtime.h>

typedef unsigned short u16;
typedef __attribute__((ext_vector_type(8))) short bf16x8;
typedef __attribute__((ext_vector_type(4))) float f32x4;
typedef __attribute__((ext_vector_type(16))) float f32x16;
typedef __attribute__((ext_vector_type(4))) unsigned u32x4;

#define B_ 2
#define N_ 2048
#define C_ 1024
#define H_ 16
#define D_ 64
#define M_ (B_ * N_)  // 4096

// 0.125 * log2(e): fold the 1/sqrt(D) scale and exp->exp2 conversion into Q.
#define QSCALE 0.18033688011114336f

#define EXP2R(x) __builtin_amdgcn_exp2f(x)

__device__ __forceinline__ u16 f2bf(float f) {
    union { float f; unsigned u; } x; x.f = f;
    return (u16)((x.u + 0x8000u) >> 16);
}
__device__ __forceinline__ unsigned pack2bf(float a, float b) {
    union { float f; unsigned u; } x, y; x.f = a; y.f = b;
    return __builtin_amdgcn_perm(y.u + 0x8000u, x.u + 0x8000u, 0x07060302);
}
// single-op pack (RTNE), verified correct in r6
__device__ __forceinline__ unsigned cvtpk2bf(float a, float b) {
    unsigned r;
    asm("v_cvt_pk_bf16_f32 %0, %1, %2" : "=v"(r) : "v"(a), "v"(b));
    return r;
}

__device__ __forceinline__ void async_copy16(const void* gsrc, void* ldst) {
    __builtin_amdgcn_global_load_lds(
        (__attribute__((address_space(1))) void*)gsrc,
        (__attribute__((address_space(3))) void*)ldst,
        16, 0, 0);
}

// ---------------- fused cast fp32 -> bf16 (x, w_qkv, w_proj in one launch) ----------------
__global__ void cast3_kernel(const float* __restrict__ x, const float* __restrict__ wq,
                             const float* __restrict__ wp, u16* __restrict__ xo,
                             u16* __restrict__ wqo, u16* __restrict__ wpo) {
    int b = blockIdx.x;
    const float* s; u16* d;
    if (b < 4096)      { s = x;  d = xo;  }
    else if (b < 7168) { s = wq; d = wqo; b -= 4096; }
    else               { s = wp; d = wpo; b -= 7168; }
    int i = (b * 256 + threadIdx.x) * 4;
    const float4 v = *(const float4*)(s + i);
    uint2 o;
    o.x = pack2bf(v.x, v.y);
    o.y = pack2bf(v.z, v.w);
    *(uint2*)(d + i) = o;
}

// ---------------- gemm0: C = A * B^T, 128x128 tiles (proven m97 structure) ----------------
// Scatter epilogue: q (pre-scaled) / k into [B,H,N,D]; V TRANSPOSED into vt [B,H,D,N].
// Bijective XCD swizzle (grid 768 % 8 == 0).
__global__ __launch_bounds__(256, 3) void gemm_qkv(
    const u16* __restrict__ A, const u16* __restrict__ Bm,
    u16* __restrict__ qo, u16* __restrict__ ko, u16* __restrict__ vt) {
    __shared__ u16 As[128 * 64];
    __shared__ u16 Bs[128 * 64];
    const int K = C_, ntiles_n = 24;
    const int tid = threadIdx.x, lane = tid & 63, w = tid >> 6;
    const int cpx = gridDim.x >> 3;
    const int sbid = (blockIdx.x & 7) * cpx + (blockIdx.x >> 3);
    const int bx = sbid % ntiles_n, by = sbid / ntiles_n;
    const int m0 = by * 128, n0 = bx * 128;
    const int wm = w >> 1, wn = w & 1;
    const int q16 = lane >> 4, l15 = lane & 15;
    const int r0 = lane >> 3, c0 = (lane & 7) * 8;
    f32x4 acc[4][4] = {};

    for (int k0 = 0; k0 < K; k0 += 64) {
#pragma unroll
        for (int i = 0; i < 4; ++i) {
            int blk = w * 4 + i;
            int r = blk * 8 + r0;
            async_copy16(A + (size_t)(m0 + r) * K + k0 + c0, (char*)As + blk * 1024);
            async_copy16(Bm + (size_t)(n0 + r) * K + k0 + c0, (char*)Bs + blk * 1024);
        }
        __builtin_amdgcn_s_waitcnt(0);
        __syncthreads();
#pragma unroll
        for (int ks = 0; ks < 2; ++ks) {
            bf16x8 af[4], bf[4];
#pragma unroll
            for (int i = 0; i < 4; ++i) {
                af[i] = *(const bf16x8*)&As[(wm * 64 + i * 16 + l15) * 64 + ks * 32 + q16 * 8];
                bf[i] = *(const bf16x8*)&Bs[(wn * 64 + i * 16 + l15) * 64 + ks * 32 + q16 * 8];
            }
#pragma unroll
            for (int mi = 0; mi < 4; ++mi)
#pragma unroll
                for (int ni = 0; ni < 4; ++ni)
                    acc[mi][ni] = __builtin_amdgcn_mfma_f32_16x16x32_bf16(af[mi], bf[ni], acc[mi][ni], 0, 0, 0);
        }
        __syncthreads();
    }

#pragma unroll
    for (int mi = 0; mi < 4; ++mi) {
#pragma unroll
        for (int ni = 0; ni < 4; ++ni) {
            int n_g = n0 + wn * 64 + ni * 16 + l15;
            int which = n_g >> 10;           // block-uniform: 0=q 1=k 2=v
            int h = (n_g >> 6) & 15;
            int d = n_g & 63;
            int m_base = m0 + wm * 64 + mi * 16 + q16 * 4;
            int b = m_base >> 11;
            int nn0 = m_base & 2047;
            if (which == 2) {
                uint2 pk;
                pk.x = pack2bf(acc[mi][ni][0], acc[mi][ni][1]);
                pk.y = pack2bf(acc[mi][ni][2], acc[mi][ni][3]);
                *(uint2*)(vt + ((size_t)((b * H_ + h) * D_ + d) << 11) + nn0) = pk;
            } else {
                size_t base = ((size_t)((b * H_ + h) * N_ + nn0) << 6) + d;
#pragma unroll
                for (int r = 0; r < 4; ++r) {
                    float v = acc[mi][ni][r];
                    if (which == 0) qo[base + (size_t)r * D_] = f2bf(v * QSCALE);
                    else            ko[base + (size_t)r * D_] = f2bf(v);
                }
            }
        }
    }
}

// ---------------- gemm1: out = A * B^T + bias, 128x64 tiles -------------------------------
// r8 theory: the old 128x128 grid was 256 blocks = 1 block/CU = 1 wave/SIMD (no latency
// hiding). 128x64 tiles -> 32x16 = 512 blocks = 2 blocks/CU = 2 waves/SIMD, same m97-style
// staging (A 16KB: 4 chunks/wave; B 8KB: 2 chunks/wave), LDS 24 KB. XCD-swizzled.
__global__ __launch_bounds__(256, 2) void gemm_out(
    const u16* __restrict__ A, const u16* __restrict__ Bm,
    const float* __restrict__ bias, float* __restrict__ out) {
    __shared__ u16 As[128 * 64];
    __shared__ u16 Bs[64 * 64];
    const int K = C_, Ncols = C_, ntiles_n = 16;
    const int tid = threadIdx.x, lane = tid & 63, w = tid >> 6;
    const int cpx = gridDim.x >> 3;  // 64
    const int sbid = (blockIdx.x & 7) * cpx + (blockIdx.x >> 3);
    const int bx = sbid % ntiles_n, by = sbid / ntiles_n;
    const int m0 = by * 128, n0 = bx * 64;
    const int wm = w >> 1, wn = w & 1;
    const int q16 = lane >> 4, l15 = lane & 15;
    const int r0 = lane >> 3, c0 = (lane & 7) * 8;
    f32x4 acc[4][2] = {};

    for (int k0 = 0; k0 < K; k0 += 64) {
#pragma unroll
        for (int i = 0; i < 4; ++i) {
            int blk = w * 4 + i;   // 0..15: A chunks
            int r = blk * 8 + r0;
            async_copy16(A + (size_t)(m0 + r) * K + k0 + c0, (char*)As + blk * 1024);
        }
#pragma unroll
        for (int i = 0; i < 2; ++i) {
            int blk = w * 2 + i;   // 0..7: B chunks
            int r = blk * 8 + r0;
            async_copy16(Bm + (size_t)(n0 + r) * K + k0 + c0, (char*)Bs + blk * 1024);
        }
        __builtin_amdgcn_s_waitcnt(0);
        __syncthreads();
#pragma unroll
        for (int ks = 0; ks < 2; ++ks) {
            bf16x8 af[4], bf[2];
#pragma unroll
            for (int i = 0; i < 4; ++i)
                af[i] = *(const bf16x8*)&As[(wm * 64 + i * 16 + l15) * 64 + ks * 32 + q16 * 8];
#pragma unroll
            for (int i = 0; i < 2; ++i)
                bf[i] = *(const bf16x8*)&Bs[(wn * 32 + i * 16 + l15) * 64 + ks * 32 + q16 * 8];
#pragma unroll
            for (int mi = 0; mi < 4; ++mi)
#pragma unroll
                for (int ni = 0; ni < 2; ++ni)
                    acc[mi][ni] = __builtin_amdgcn_mfma_f32_16x16x32_bf16(af[mi], bf[ni], acc[mi][ni], 0, 0, 0);
        }
        __syncthreads();
    }

#pragma unroll
    for (int mi = 0; mi < 4; ++mi) {
#pragma unroll
        for (int ni = 0; ni < 2; ++ni) {
            int n_g = n0 + wn * 32 + ni * 16 + l15;
#pragma unroll
            for (int r = 0; r < 4; ++r) {
                int m_g = m0 + wm * 64 + mi * 16 + q16 * 4 + r;
                out[(size_t)m_g * Ncols + n_g] = acc[mi][ni][r] + bias[n_g];
            }
        }
    }
}

// ---------------- attention: r5 exact (best measured: 47.3 us) ---------------------------
// 32x32 MFMA, in-register P (no Ps LDS), 8 waves x 32 q, grid 256, XCD-swizzled.
// QK C-layout (m74/m101): col=lane&31=q, row=key=(reg&3)+8*(reg>>2)+4*hi.
__global__ __launch_bounds__(512, 1) void attn_kernel(
    const u16* __restrict__ Q, const u16* __restrict__ K,
    const u16* __restrict__ VT, u16* __restrict__ O) {
    __shared__ u16 Ks[2][2][64 * 64];  // [buf][sub][key][d], 16B-block swizzle (mask 7)
    __shared__ u16 Vs[2][2][64 * 64];  // [buf][sub][d][key], 16B-block swizzle (mask 7)
    const int tid = threadIdx.x, lane = tid & 63, w = tid >> 6;
    const int l31 = lane & 31, hi = lane >> 5, l7 = l31 & 7;
    const int bid = blockIdx.x;
    // bijective XCD swizzle over 256 blocks: xcd=bid&7, qb=(bid>>3)&7, hi4=bid>>6
    const int bh = (bid & 7) * 4 + (bid >> 6);
    const int q0 = ((bid >> 3) & 7) * 256;
    const size_t head = (size_t)bh * N_ * D_;
    const int lr3 = lane >> 3, lc7 = lane & 7;

    auto stage = [&](int kt, int buf) {
        int key0 = kt * 128;
        int row = w * 8 + lr3;  // wave w owns 1KB chunk w of each 8KB sub-tile
#pragma unroll
        for (int s = 0; s < 2; ++s) {
            async_copy16(K + head + (size_t)(key0 + s * 64 + row) * D_ + (lc7 ^ lr3) * 8,
                         (char*)Ks[buf][s] + w * 1024);
            async_copy16(VT + head + (size_t)row * N_ + key0 + s * 64 + (lc7 ^ lr3) * 8,
                         (char*)Vs[buf][s] + w * 1024);
        }
    };

    // prologue: Q B-fragments (lane: q = q0+w*32+l31, d-slice ds*16+hi*8) + K/V(0) stage.
    bf16x8 qf[4];
#pragma unroll
    for (int ds = 0; ds < 4; ++ds)
        qf[ds] = *(const bf16x8*)(Q + head + (size_t)(q0 + w * 32 + l31) * D_ + ds * 16 + hi * 8);
    stage(0, 0);
    __builtin_amdgcn_s_waitcnt(0);
    __syncthreads();

    f32x16 o_acc[2] = {};
    float rs = 0.f;

    for (int kt = 0; kt < 16; ++kt) {
        int buf = kt & 1;
        stage((kt + 1) & 15, buf ^ 1);  // prefetch next 128-key tile (kt=15 wraps, harmless)

#pragma unroll
        for (int s = 0; s < 2; ++s) {
#pragma unroll
            for (int kb2 = 0; kb2 < 2; ++kb2) {
                // QK: S^T = K·Q^T over d=64 (4 x K=16 slices); C: col=q=l31, row=key
                f32x16 st = {};
                __builtin_amdgcn_s_setprio(1);
#pragma unroll
                for (int ds = 0; ds < 4; ++ds) {
                    bf16x8 kf = *(const bf16x8*)&Ks[buf][s][(kb2 * 32 + l31) * 64 + ((ds * 2 + hi) ^ l7) * 8];
                    st = __builtin_amdgcn_mfma_f32_32x32x16_bf16(kf, qf[ds], st, 0, 0, 0);
                }
                __builtin_amdgcn_s_setprio(0);

                float p[16];
#pragma unroll
                for (int i = 0; i < 16; ++i) p[i] = EXP2R(st[i]);
#pragma unroll
                for (int i = 0; i < 16; ++i) rs += p[i];

                // in-register PV A-fragments: pack pairs, swap halves across lane+-32
                unsigned a0 = cvtpk2bf(p[0], p[1]),   b0 = cvtpk2bf(p[4], p[5]);
                unsigned a1 = cvtpk2bf(p[2], p[3]),   b1 = cvtpk2bf(p[6], p[7]);
                unsigned a2 = cvtpk2bf(p[8], p[9]),   b2 = cvtpk2bf(p[12], p[13]);
                unsigned a3 = cvtpk2bf(p[10], p[11]), b3 = cvtpk2bf(p[14], p[15]);
                asm("v_permlane32_swap_b32 %0, %1" : "+v"(a0), "+v"(b0));
                asm("v_permlane32_swap_b32 %0, %1" : "+v"(a1), "+v"(b1));
                asm("v_permlane32_swap_b32 %0, %1" : "+v"(a2), "+v"(b2));
                asm("v_permlane32_swap_b32 %0, %1" : "+v"(a3), "+v"(b3));
                union { u32x4 u; bf16x8 v; } af0, af1;
                af0.u = (u32x4){a0, a1, b0, b1};  // keys kb2*32 + 0..15
                af1.u = (u32x4){a2, a3, b2, b3};  // keys kb2*32 + 16..31

                // PV: O += P·V; B from Vs rows d=l31+32*db, keys kb2*32+ks*16+hi*8..+8
                __builtin_amdgcn_s_setprio(1);
#pragma unroll
                for (int db = 0; db < 2; ++db) {
                    bf16x8 vf0 = *(const bf16x8*)&Vs[buf][s][(db * 32 + l31) * 64 + ((kb2 * 4 + hi) ^ l7) * 8];
                    o_acc[db] = __builtin_amdgcn_mfma_f32_32x32x16_bf16(af0.v, vf0, o_acc[db], 0, 0, 0);
                    bf16x8 vf1 = *(const bf16x8*)&Vs[buf][s][(db * 32 + l31) * 64 + ((kb2 * 4 + 2 + hi) ^ l7) * 8];
                    o_acc[db] = __builtin_amdgcn_mfma_f32_32x32x16_bf16(af1.v, vf1, o_acc[db], 0, 0, 0);
                }
                __builtin_amdgcn_s_setprio(0);
            }
        }

        // single full drain + barrier per 128 keys
        __builtin_amdgcn_s_waitcnt(0);
        __syncthreads();
    }

    // rowsum: lane (hi, l31) holds partial for q=l31 over its key set; fold hi halves.
    rs += __shfl_xor(rs, 32);
    float rsi = 1.0f / rs;  // valid for q = l31 on every lane

    const int b = bh >> 4, h = bh & 15;
#pragma unroll
    for (int reg = 0; reg < 16; ++reg) {
        int qrow = (reg & 3) + 8 * (reg >> 2) + 4 * hi;  // O row for this acc reg
        float inv = __shfl(rsi, qrow);                    // lane qrow holds 1/rs for q=qrow
        int qg = q0 + w * 32 + qrow;
#pragma unroll
        for (int db = 0; db < 2; ++db) {
            int d = db * 32 + l31;
            O[((size_t)(b * N_ + qg) << 10) + h * 64 + d] = f2bf(o_acc[db][reg] * inv);
        }
    }
}

extern "C" void kernel_launch(void* const* d_in, const int* in_sizes, int n_in,
                              void* d_out, int out_size, void* d_ws, size_t ws_size,
                              hipStream_t stream) {
    const float* x      = (const float*)d_in[0];
    const float* w_qkv  = (const float*)d_in[1];
    const float* w_proj = (const float*)d_in[2];
    const float* b_proj = (const float*)d_in[3];
    float* out = (float*)d_out;

    char* ws = (char*)d_ws;
    const size_t MB = 1024 * 1024;
    u16* x_bf     = (u16*)(ws + 0 * MB);   // 8 MB
    u16* wqkv_bf  = (u16*)(ws + 8 * MB);   // 6 MB
    u16* wproj_bf = (u16*)(ws + 14 * MB);  // 2 MB
    u16* q_bf     = (u16*)(ws + 16 * MB);  // 8 MB [B,H,N,D]
    u16* k_bf     = (u16*)(ws + 24 * MB);  // 8 MB [B,H,N,D]
    u16* vt_bf    = (u16*)(ws + 32 * MB);  // 8 MB [B,H,D,N]
    u16* ao_bf    = (u16*)(ws + 40 * MB);  // 8 MB [B,N,C]

    cast3_kernel<<<8192, 256, 0, stream>>>(x, w_qkv, w_proj, x_bf, wqkv_bf, wproj_bf);

    gemm_qkv<<<768, 256, 0, stream>>>(x_bf, wqkv_bf, q_bf, k_bf, vt_bf);

    attn_kernel<<<256, 512, 0, stream>>>(q_bf, k_bf, vt_bf, ao_bf);

    gemm_out<<<512, 256, 0, stream>>>(ao_bf, wproj_bf, b_proj, out);
}

// Round 11
// 175.396 us; speedup vs baseline: 1.1039x; 1.0194x over previous
//
#include <hip/hip_runtime.h>

typedef unsigned short u16;
typedef __attribute__((ext_vector_type(8))) short bf16x8;
typedef __attribute__((ext_vector_type(4))) float f32x4;
typedef __attribute__((ext_vector_type(16))) float f32x16;
typedef __attribute__((ext_vector_type(4))) unsigned u32x4;

#define B_ 2
#define N_ 2048
#define C_ 1024
#define H_ 16
#define D_ 64
#define M_ (B_ * N_)  // 4096

// 0.125 * log2(e): fold the 1/sqrt(D) scale and exp->exp2 conversion into Q.
#define QSCALE 0.18033688011114336f

#define EXP2R(x) __builtin_amdgcn_exp2f(x)

__device__ __forceinline__ u16 f2bf(float f) {
    union { float f; unsigned u; } x; x.f = f;
    return (u16)((x.u + 0x8000u) >> 16);
}
__device__ __forceinline__ unsigned pack2bf(float a, float b) {
    union { float f; unsigned u; } x, y; x.f = a; y.f = b;
    return __builtin_amdgcn_perm(y.u + 0x8000u, x.u + 0x8000u, 0x07060302);
}
// single-op pack (RTNE), verified correct in r6
__device__ __forceinline__ unsigned cvtpk2bf(float a, float b) {
    unsigned r;
    asm("v_cvt_pk_bf16_f32 %0, %1, %2" : "=v"(r) : "v"(a), "v"(b));
    return r;
}

__device__ __forceinline__ void async_copy16(const void* gsrc, void* ldst) {
    __builtin_amdgcn_global_load_lds(
        (__attribute__((address_space(1))) void*)gsrc,
        (__attribute__((address_space(3))) void*)ldst,
        16, 0, 0);
}

// ---------------- fused cast fp32 -> bf16 (x, w_qkv, w_proj in one launch) ----------------
__global__ void cast3_kernel(const float* __restrict__ x, const float* __restrict__ wq,
                             const float* __restrict__ wp, u16* __restrict__ xo,
                             u16* __restrict__ wqo, u16* __restrict__ wpo) {
    int b = blockIdx.x;
    const float* s; u16* d;
    if (b < 4096)      { s = x;  d = xo;  }
    else if (b < 7168) { s = wq; d = wqo; b -= 4096; }
    else               { s = wp; d = wpo; b -= 7168; }
    int i = (b * 256 + threadIdx.x) * 4;
    const float4 v = *(const float4*)(s + i);
    uint2 o;
    o.x = pack2bf(v.x, v.y);
    o.y = pack2bf(v.z, v.w);
    *(uint2*)(d + i) = o;
}

// ---------------- gemm0: 8-phase 256x256 schedule (T2 swizzle + T3/T4 counted vmcnt + T5) --
// C = A(x_bf [4096,1024]) * B(wqkv_bf [3072,1024])^T, scatter epilogue into q/k/vt.
// grid 192 (16x12), 512 thr (8 waves, 2M x 4N), LDS 128 KB = 2 regions x 4 half-tile slots
// {Ah0,Ah1,Bh0,Bh1} of [128][64] bf16, XOR-swizzled (source (lc7^lr3), read ^l7).
// r10 WAR-fix: A slots are read in ph1 AND ph3 (halves mh=0/1), so Ah0(T+2) must stage at
// ph4 (not ph2) and Ah0(T+3) at ph8 (not ph6). Ledger (re-verified, HT granularity):
//   in-flight entering ph1 = {Bh0,Bh1,Ah0}(T+1); ph1 +Ah1(T+1); ph3 +Bh0(T+2);
//   ph4 +Bh1(T+2)+Ah0(T+2), vmcnt(6) -> tile T+1 landed before ph5 reads it;
//   ph5 +Ah1(T+2); ph7 +Bh0(T+3); ph8 +Bh1(T+3)+Ah0(T+3), vmcnt(6) -> tile T+2 landed.
// WAR: every slot staged strictly after its last reader phase (A free after ph3/ph7,
// B free after ph2/ph6), with a barrier between read-completion and stage issue.
__global__ __launch_bounds__(512, 2) void gemm_qkv8(
    const u16* __restrict__ A, const u16* __restrict__ Bm,
    u16* __restrict__ qo, u16* __restrict__ ko, u16* __restrict__ vt) {
    __shared__ u16 L[2][4][8192];  // [region][slot][128*64]
    const int tid = threadIdx.x, lane = tid & 63, w = tid >> 6;  // 8 waves
    const int wm = w >> 2, wn = w & 3;
    const int q16 = lane >> 4, l15 = lane & 15, l7 = lane & 7;
    const int lr3 = lane >> 3, lc7 = lane & 7;
    const int sbid = (blockIdx.x & 7) * 24 + (blockIdx.x >> 3);  // XCD swizzle (192%8==0)
    const int bx = sbid % 12, by = sbid / 12;
    const int m0 = by * 256, n0 = bx * 256;
    const int cswz8 = (lc7 ^ lr3) * 8;

    auto stageHT = [&](int t, int isB, int h) {  // one 16KB half-tile, 2 loads/thread
        if (t > 15) return;
        const u16* src = isB ? Bm : A;
        int base_row = (isB ? n0 : m0) + h * 128;
#pragma unroll
        for (int i = 0; i < 2; ++i) {
            int c = w * 2 + i;  // 1KB chunk 0..15 (8 rows x 128B)
            async_copy16(src + (size_t)(base_row + c * 8 + lr3) * 1024 + t * 64 + cswz8,
                         (char*)L + ((t & 1) * 4 + isB * 2 + h) * 16384 + c * 1024);
        }
    };

    // prologue: tile0 (4 halves) + tile1 (3 halves); drain to 3 HT; barrier.
    stageHT(0, 0, 0); stageHT(0, 1, 0); stageHT(0, 1, 1); stageHT(0, 0, 1);
    stageHT(1, 0, 0); stageHT(1, 1, 0); stageHT(1, 1, 1);
    asm volatile("s_waitcnt vmcnt(6)" ::: "memory");
    __builtin_amdgcn_s_barrier();

    f32x4 acc[8][4] = {};
    const int aRow = l15 * 64;
    const int colsw0 = (q16 ^ l7) * 8, colsw1 = ((4 + q16) ^ l7) * 8;
    const u16* LA[2] = { &L[0][wm][0], &L[1][wm][0] };
    const u16* LB[2] = { &L[0][2 + (wn >> 1)][0], &L[1][2 + (wn >> 1)][0] };
    const int bOff = (wn & 1) * 4096;

    bf16x8 Af[4][2], Bf0[2][2], Bf1[2][2];

    auto readA = [&](int P, int mh) {
#pragma unroll
        for (int i = 0; i < 4; ++i) {
            Af[i][0] = *(const bf16x8*)(LA[P] + (mh * 64 + i * 16) * 64 + aRow + colsw0);
            Af[i][1] = *(const bf16x8*)(LA[P] + (mh * 64 + i * 16) * 64 + aRow + colsw1);
        }
    };
    auto readB = [&](int P, int nh, bf16x8 (*Bf)[2]) {
#pragma unroll
        for (int j = 0; j < 2; ++j) {
            Bf[j][0] = *(const bf16x8*)(LB[P] + bOff + (nh * 32 + j * 16) * 64 + aRow + colsw0);
            Bf[j][1] = *(const bf16x8*)(LB[P] + bOff + (nh * 32 + j * 16) * 64 + aRow + colsw1);
        }
    };
    auto mfma16 = [&](int mh, int nh, bf16x8 (*Bf)[2]) {
        __builtin_amdgcn_s_setprio(1);
#pragma unroll
        for (int i = 0; i < 4; ++i)
#pragma unroll
            for (int j = 0; j < 2; ++j)
#pragma unroll
                for (int ks = 0; ks < 2; ++ks)
                    acc[mh * 4 + i][nh * 2 + j] = __builtin_amdgcn_mfma_f32_16x16x32_bf16(
                        Af[i][ks], Bf[j][ks], acc[mh * 4 + i][nh * 2 + j], 0, 0, 0);
        __builtin_amdgcn_s_setprio(0);
    };

    for (int it = 0; it < 8; ++it) {
        const int T = 2 * it;
        // ph1: quadrant (m0,n0) of tile T (region 0); stage Ah1(T+1)
        readA(0, 0); readB(0, 0, Bf0); stageHT(T + 1, 0, 1);
        __builtin_amdgcn_s_barrier();
        mfma16(0, 0, Bf0);
        __builtin_amdgcn_s_barrier();
        // ph2: (m0,n1); no stage (A slot still has a reader at ph3)
        readB(0, 1, Bf1);
        __builtin_amdgcn_s_barrier();
        mfma16(0, 1, Bf1);
        __builtin_amdgcn_s_barrier();
        // ph3: (m1,n1); stage Bh0(T+2) (B slot free after ph2)
        readA(0, 1); stageHT(T + 2, 1, 0);
        __builtin_amdgcn_s_barrier();
        mfma16(1, 1, Bf1);
        __builtin_amdgcn_s_barrier();
        // ph4: (m1,n0); stage Bh1(T+2) + Ah0(T+2) (A slot free after ph3); counted drain
        stageHT(T + 2, 1, 1); stageHT(T + 2, 0, 0);
        __builtin_amdgcn_s_barrier();
        mfma16(1, 0, Bf0);
        if (it < 7) { asm volatile("s_waitcnt vmcnt(6)" ::: "memory"); }
        else        { asm volatile("s_waitcnt vmcnt(0)" ::: "memory"); }
        __builtin_amdgcn_s_barrier();
        // ph5: (m0,n0) of tile T+1 (region 1); stage Ah1(T+2)
        readA(1, 0); readB(1, 0, Bf0); stageHT(T + 2, 0, 1);
        __builtin_amdgcn_s_barrier();
        mfma16(0, 0, Bf0);
        __builtin_amdgcn_s_barrier();
        // ph6: (m0,n1); no stage (region1 A slot still has a reader at ph7)
        readB(1, 1, Bf1);
        __builtin_amdgcn_s_barrier();
        mfma16(0, 1, Bf1);
        __builtin_amdgcn_s_barrier();
        // ph7: (m1,n1); stage Bh0(T+3) (region1 B slot free after ph6)
        readA(1, 1); stageHT(T + 3, 1, 0);
        __builtin_amdgcn_s_barrier();
        mfma16(1, 1, Bf1);
        __builtin_amdgcn_s_barrier();
        // ph8: (m1,n0); stage Bh1(T+3) + Ah0(T+3) (region1 A slot free after ph7); drain
        stageHT(T + 3, 1, 1); stageHT(T + 3, 0, 0);
        __builtin_amdgcn_s_barrier();
        mfma16(1, 0, Bf0);
        if (it < 7) { asm volatile("s_waitcnt vmcnt(6)" ::: "memory"); }
        __builtin_amdgcn_s_barrier();
    }

    // epilogue: scatter q (pre-scaled) / k into [B,H,N,D]; V transposed into vt [B,H,D,N].
    // n-tile is 256 cols: `which` block-uniform, h wave-uniform; m-tile never straddles b.
#pragma unroll
    for (int fm = 0; fm < 8; ++fm) {
#pragma unroll
        for (int fn = 0; fn < 4; ++fn) {
            int n_g = n0 + wn * 64 + fn * 16 + l15;
            int which = n_g >> 10;
            int h = (n_g >> 6) & 15;
            int d = n_g & 63;
            int m_base = m0 + wm * 128 + fm * 16 + q16 * 4;
            int b = m_base >> 11;
            int nn0 = m_base & 2047;
            if (which == 2) {
                uint2 pk;
                pk.x = pack2bf(acc[fm][fn][0], acc[fm][fn][1]);
                pk.y = pack2bf(acc[fm][fn][2], acc[fm][fn][3]);
                *(uint2*)(vt + ((size_t)((b * H_ + h) * D_ + d) << 11) + nn0) = pk;
            } else {
                size_t base = ((size_t)((b * H_ + h) * N_ + nn0) << 6) + d;
#pragma unroll
                for (int r = 0; r < 4; ++r) {
                    float v = acc[fm][fn][r];
                    if (which == 0) qo[base + (size_t)r * D_] = f2bf(v * QSCALE);
                    else            ko[base + (size_t)r * D_] = f2bf(v);
                }
            }
        }
    }
}

// ---------------- gemm1: out = A * B^T + bias, 128x64 tiles (r9, proven) ------------------
__global__ __launch_bounds__(256, 2) void gemm_out(
    const u16* __restrict__ A, const u16* __restrict__ Bm,
    const float* __restrict__ bias, float* __restrict__ out) {
    __shared__ u16 As[128 * 64];
    __shared__ u16 Bs[64 * 64];
    const int K = C_, Ncols = C_, ntiles_n = 16;
    const int tid = threadIdx.x, lane = tid & 63, w = tid >> 6;
    const int cpx = gridDim.x >> 3;  // 64
    const int sbid = (blockIdx.x & 7) * cpx + (blockIdx.x >> 3);
    const int bx = sbid % ntiles_n, by = sbid / ntiles_n;
    const int m0 = by * 128, n0 = bx * 64;
    const int wm = w >> 1, wn = w & 1;
    const int q16 = lane >> 4, l15 = lane & 15;
    const int r0 = lane >> 3, c0 = (lane & 7) * 8;
    f32x4 acc[4][2] = {};

    for (int k0 = 0; k0 < K; k0 += 64) {
#pragma unroll
        for (int i = 0; i < 4; ++i) {
            int blk = w * 4 + i;   // 0..15: A chunks
            int r = blk * 8 + r0;
            async_copy16(A + (size_t)(m0 + r) * K + k0 + c0, (char*)As + blk * 1024);
        }
#pragma unroll
        for (int i = 0; i < 2; ++i) {
            int blk = w * 2 + i;   // 0..7: B chunks
            int r = blk * 8 + r0;
            async_copy16(Bm + (size_t)(n0 + r) * K + k0 + c0, (char*)Bs + blk * 1024);
        }
        __builtin_amdgcn_s_waitcnt(0);
        __syncthreads();
#pragma unroll
        for (int ks = 0; ks < 2; ++ks) {
            bf16x8 af[4], bf[2];
#pragma unroll
            for (int i = 0; i < 4; ++i)
                af[i] = *(const bf16x8*)&As[(wm * 64 + i * 16 + l15) * 64 + ks * 32 + q16 * 8];
#pragma unroll
            for (int i = 0; i < 2; ++i)
                bf[i] = *(const bf16x8*)&Bs[(wn * 32 + i * 16 + l15) * 64 + ks * 32 + q16 * 8];
#pragma unroll
            for (int mi = 0; mi < 4; ++mi)
#pragma unroll
                for (int ni = 0; ni < 2; ++ni)
                    acc[mi][ni] = __builtin_amdgcn_mfma_f32_16x16x32_bf16(af[mi], bf[ni], acc[mi][ni], 0, 0, 0);
        }
        __syncthreads();
    }

#pragma unroll
    for (int mi = 0; mi < 4; ++mi) {
#pragma unroll
        for (int ni = 0; ni < 2; ++ni) {
            int n_g = n0 + wn * 32 + ni * 16 + l15;
#pragma unroll
            for (int r = 0; r < 4; ++r) {
                int m_g = m0 + wm * 64 + mi * 16 + q16 * 4 + r;
                out[(size_t)m_g * Ncols + n_g] = acc[mi][ni][r] + bias[n_g];
            }
        }
    }
}

// ---------------- attention: r5/r9 exact (best measured: 45.0 us) -------------------------
// 32x32 MFMA, in-register P (no Ps LDS), 8 waves x 32 q, grid 256, XCD-swizzled.
// QK C-layout (m74/m101): col=lane&31=q, row=key=(reg&3)+8*(reg>>2)+4*hi.
__global__ __launch_bounds__(512, 1) void attn_kernel(
    const u16* __restrict__ Q, const u16* __restrict__ K,
    const u16* __restrict__ VT, u16* __restrict__ O) {
    __shared__ u16 Ks[2][2][64 * 64];  // [buf][sub][key][d], 16B-block swizzle (mask 7)
    __shared__ u16 Vs[2][2][64 * 64];  // [buf][sub][d][key], 16B-block swizzle (mask 7)
    const int tid = threadIdx.x, lane = tid & 63, w = tid >> 6;
    const int l31 = lane & 31, hi = lane >> 5, l7 = l31 & 7;
    const int bid = blockIdx.x;
    const int bh = (bid & 7) * 4 + (bid >> 6);
    const int q0 = ((bid >> 3) & 7) * 256;
    const size_t head = (size_t)bh * N_ * D_;
    const int lr3 = lane >> 3, lc7 = lane & 7;

    auto stage = [&](int kt, int buf) {
        int key0 = kt * 128;
        int row = w * 8 + lr3;
#pragma unroll
        for (int s = 0; s < 2; ++s) {
            async_copy16(K + head + (size_t)(key0 + s * 64 + row) * D_ + (lc7 ^ lr3) * 8,
                         (char*)Ks[buf][s] + w * 1024);
            async_copy16(VT + head + (size_t)row * N_ + key0 + s * 64 + (lc7 ^ lr3) * 8,
                         (char*)Vs[buf][s] + w * 1024);
        }
    };

    bf16x8 qf[4];
#pragma unroll
    for (int ds = 0; ds < 4; ++ds)
        qf[ds] = *(const bf16x8*)(Q + head + (size_t)(q0 + w * 32 + l31) * D_ + ds * 16 + hi * 8);
    stage(0, 0);
    __builtin_amdgcn_s_waitcnt(0);
    __syncthreads();

    f32x16 o_acc[2] = {};
    float rs = 0.f;

    for (int kt = 0; kt < 16; ++kt) {
        int buf = kt & 1;
        stage((kt + 1) & 15, buf ^ 1);

#pragma unroll
        for (int s = 0; s < 2; ++s) {
#pragma unroll
            for (int kb2 = 0; kb2 < 2; ++kb2) {
                f32x16 st = {};
                __builtin_amdgcn_s_setprio(1);
#pragma unroll
                for (int ds = 0; ds < 4; ++ds) {
                    bf16x8 kf = *(const bf16x8*)&Ks[buf][s][(kb2 * 32 + l31) * 64 + ((ds * 2 + hi) ^ l7) * 8];
                    st = __builtin_amdgcn_mfma_f32_32x32x16_bf16(kf, qf[ds], st, 0, 0, 0);
                }
                __builtin_amdgcn_s_setprio(0);

                float p[16];
#pragma unroll
                for (int i = 0; i < 16; ++i) p[i] = EXP2R(st[i]);
#pragma unroll
                for (int i = 0; i < 16; ++i) rs += p[i];

                unsigned a0 = cvtpk2bf(p[0], p[1]),   b0 = cvtpk2bf(p[4], p[5]);
                unsigned a1 = cvtpk2bf(p[2], p[3]),   b1 = cvtpk2bf(p[6], p[7]);
                unsigned a2 = cvtpk2bf(p[8], p[9]),   b2 = cvtpk2bf(p[12], p[13]);
                unsigned a3 = cvtpk2bf(p[10], p[11]), b3 = cvtpk2bf(p[14], p[15]);
                asm("v_permlane32_swap_b32 %0, %1" : "+v"(a0), "+v"(b0));
                asm("v_permlane32_swap_b32 %0, %1" : "+v"(a1), "+v"(b1));
                asm("v_permlane32_swap_b32 %0, %1" : "+v"(a2), "+v"(b2));
                asm("v_permlane32_swap_b32 %0, %1" : "+v"(a3), "+v"(b3));
                union { u32x4 u; bf16x8 v; } af0, af1;
                af0.u = (u32x4){a0, a1, b0, b1};
                af1.u = (u32x4){a2, a3, b2, b3};

                __builtin_amdgcn_s_setprio(1);
#pragma unroll
                for (int db = 0; db < 2; ++db) {
                    bf16x8 vf0 = *(const bf16x8*)&Vs[buf][s][(db * 32 + l31) * 64 + ((kb2 * 4 + hi) ^ l7) * 8];
                    o_acc[db] = __builtin_amdgcn_mfma_f32_32x32x16_bf16(af0.v, vf0, o_acc[db], 0, 0, 0);
                    bf16x8 vf1 = *(const bf16x8*)&Vs[buf][s][(db * 32 + l31) * 64 + ((kb2 * 4 + 2 + hi) ^ l7) * 8];
                    o_acc[db] = __builtin_amdgcn_mfma_f32_32x32x16_bf16(af1.v, vf1, o_acc[db], 0, 0, 0);
                }
                __builtin_amdgcn_s_setprio(0);
            }
        }

        __builtin_amdgcn_s_waitcnt(0);
        __syncthreads();
    }

    rs += __shfl_xor(rs, 32);
    float rsi = 1.0f / rs;

    const int b = bh >> 4, h = bh & 15;
#pragma unroll
    for (int reg = 0; reg < 16; ++reg) {
        int qrow = (reg & 3) + 8 * (reg >> 2) + 4 * hi;
        float inv = __shfl(rsi, qrow);
        int qg = q0 + w * 32 + qrow;
#pragma unroll
        for (int db = 0; db < 2; ++db) {
            int d = db * 32 + l31;
            O[((size_t)(b * N_ + qg) << 10) + h * 64 + d] = f2bf(o_acc[db][reg] * inv);
        }
    }
}

extern "C" void kernel_launch(void* const* d_in, const int* in_sizes, int n_in,
                              void* d_out, int out_size, void* d_ws, size_t ws_size,
                              hipStream_t stream) {
    const float* x      = (const float*)d_in[0];
    const float* w_qkv  = (const float*)d_in[1];
    const float* w_proj = (const float*)d_in[2];
    const float* b_proj = (const float*)d_in[3];
    float* out = (float*)d_out;

    char* ws = (char*)d_ws;
    const size_t MB = 1024 * 1024;
    u16* x_bf     = (u16*)(ws + 0 * MB);   // 8 MB
    u16* wqkv_bf  = (u16*)(ws + 8 * MB);   // 6 MB
    u16* wproj_bf = (u16*)(ws + 14 * MB);  // 2 MB
    u16* q_bf     = (u16*)(ws + 16 * MB);  // 8 MB [B,H,N,D]
    u16* k_bf     = (u16*)(ws + 24 * MB);  // 8 MB [B,H,N,D]
    u16* vt_bf    = (u16*)(ws + 32 * MB);  // 8 MB [B,H,D,N]
    u16* ao_bf    = (u16*)(ws + 40 * MB);  // 8 MB [B,N,C]

    cast3_kernel<<<8192, 256, 0, stream>>>(x, w_qkv, w_proj, x_bf, wqkv_bf, wproj_bf);

    gemm_qkv8<<<192, 512, 0, stream>>>(x_bf, wqkv_bf, q_bf, k_bf, vt_bf);

    attn_kernel<<<256, 512, 0, stream>>>(q_bf, k_bf, vt_bf, ao_bf);

    gemm_out<<<512, 256, 0, stream>>>(ao_bf, wproj_bf, b_proj, out);
}